// Round 1
// baseline (471.408 us; speedup 1.0000x reference)
//
#include <hip/hip_runtime.h>
#include <cstdint>
#include <cstddef>

typedef short bf16x8 __attribute__((ext_vector_type(8)));
typedef float f32x4 __attribute__((ext_vector_type(4)));
typedef unsigned short u16;
typedef u16 u16x4v __attribute__((ext_vector_type(4)));

#define SEQ 2048

static __device__ __forceinline__ u16 f2bf(float f) {
  uint32_t u = __builtin_bit_cast(uint32_t, f);
  u += 0x7fffu + ((u >> 16) & 1u);
  return (u16)(u >> 16);
}
static __device__ __forceinline__ float bf2f(u16 v) {
  uint32_t u = ((uint32_t)v) << 16;
  return __builtin_bit_cast(float, u);
}

#define MFMA_BF16(a, b, c) __builtin_amdgcn_mfma_f32_16x16x32_bf16((a), (b), (c), 0, 0, 0)

static __device__ __forceinline__ void gload_lds16(const void* g, void* l) {
  __builtin_amdgcn_global_load_lds((const __attribute__((address_space(1))) void*)g,
                                   (__attribute__((address_space(3))) void*)l, 16, 0, 0);
}

// ---------------------------------------------------------------------------
// fp32 -> bf16 conversion of x and weights (wq,wk,wv packed into one [3072][1024])
// ---------------------------------------------------------------------------
__global__ __launch_bounds__(256) void cvt_kernel(
    const float4* __restrict__ x, const float4* __restrict__ wq,
    const float4* __restrict__ wk, const float4* __restrict__ wv,
    const float4* __restrict__ wo, u16x4v* __restrict__ xb,
    u16x4v* __restrict__ wqkvb, u16x4v* __restrict__ wob) {
  const int id = blockIdx.x * 256 + threadIdx.x;  // 3,145,728 total
  const float4* src;
  u16x4v* dst;
  if (id < 2097152) { src = x + id; dst = xb + id; }
  else if (id < 2359296) { const int j = id - 2097152; src = wq + j; dst = wqkvb + j; }
  else if (id < 2621440) { const int j = id - 2359296; src = wk + j; dst = wqkvb + 262144 + j; }
  else if (id < 2883584) { const int j = id - 2621440; src = wv + j; dst = wqkvb + 524288 + j; }
  else { const int j = id - 2883584; src = wo + j; dst = wob + j; }
  const float4 v = *src;
  u16x4v o;
  o[0] = f2bf(v.x); o[1] = f2bf(v.y); o[2] = f2bf(v.z); o[3] = f2bf(v.w);
  *dst = o;
}

// ---------------------------------------------------------------------------
// RoPE cos/sin table: tbl[s*32+i] = (cos, sin)(pos[s] * theta^(-2i/64))
// ---------------------------------------------------------------------------
__global__ __launch_bounds__(256) void rope_tbl_kernel(const int* __restrict__ tp,
                                                       float2* __restrict__ tbl) {
  const int id = blockIdx.x * 256 + threadIdx.x;  // 65536
  const int s = id >> 5, i = id & 31;
  const float pos = (float)tp[s];
  const float freq = powf(10000.0f, -(float)(2 * i) / 64.0f);
  const float ang = pos * freq;
  float sv, cv;
  sincosf(ang, &sv, &cv);
  tbl[id] = make_float2(cv, sv);
}

// ---------------------------------------------------------------------------
// bf16 GEMM, NT layout: C[m][n] = sum_k A[m][k] * Bt[n][k]
// 128x128 tile, BK=64, 4 waves, global_load_lds(16B) with XOR-swizzled LDS.
// OUT_BF16 ? write bf16 : write fp32.
// ---------------------------------------------------------------------------
template <bool OUT_BF16>
__global__ __launch_bounds__(256) void gemm_bt(const u16* __restrict__ A,
                                               const u16* __restrict__ Bt,
                                               void* __restrict__ Cout,
                                               int M, int N, int K) {
  __shared__ __align__(16) u16 As[128 * 64];
  __shared__ __align__(16) u16 Bs[128 * 64];
  const int tid = threadIdx.x;
  const int w = tid >> 6;
  const int l = tid & 63;
  const int g = l >> 4;
  const int lr = l & 15;
  const int wm = (w >> 1) * 64;
  const int wn = (w & 1) * 64;
  const long tile_m = (long)blockIdx.y * 128;
  const long tile_n = (long)blockIdx.x * 128;

  // staging: chunk c (1KB = 8 rows), lane l covers row c*8 + l/8, 16B col slot.
  // source col slot pre-swizzled so linear LDS write lands XOR-swizzled (rule 21).
  const int lrow = l >> 3;               // row within chunk (== row&7)
  const int lcolsw = (l & 7) ^ lrow;     // swizzled 16B-chunk column in global

  f32x4 acc[4][4] = {};

  for (int k0 = 0; k0 < K; k0 += 64) {
#pragma unroll
    for (int cc = 0; cc < 4; ++cc) {
      const int c = w * 4 + cc;
      const int row = c * 8 + lrow;
      gload_lds16(A + (tile_m + row) * (long)K + k0 + lcolsw * 8, As + c * 512);
      gload_lds16(Bt + (tile_n + row) * (long)K + k0 + lcolsw * 8, Bs + c * 512);
    }
    __syncthreads();
#pragma unroll
    for (int kk = 0; kk < 2; ++kk) {
      bf16x8 af[4], bfr[4];
#pragma unroll
      for (int mi = 0; mi < 4; ++mi) {
        const int row = wm + mi * 16 + lr;
        const int cc = ((kk << 2) + g) ^ (row & 7);
        af[mi] = *(const bf16x8*)((const char*)As + row * 128 + cc * 16);
      }
#pragma unroll
      for (int ni = 0; ni < 4; ++ni) {
        const int row = wn + ni * 16 + lr;
        const int cc = ((kk << 2) + g) ^ (row & 7);
        bfr[ni] = *(const bf16x8*)((const char*)Bs + row * 128 + cc * 16);
      }
#pragma unroll
      for (int mi = 0; mi < 4; ++mi)
#pragma unroll
        for (int ni = 0; ni < 4; ++ni)
          acc[mi][ni] = MFMA_BF16(af[mi], bfr[ni], acc[mi][ni]);
    }
    __syncthreads();
  }

#pragma unroll
  for (int mi = 0; mi < 4; ++mi) {
#pragma unroll
    for (int ni = 0; ni < 4; ++ni) {
      const long row0 = tile_m + wm + mi * 16 + g * 4;
      const long col = tile_n + wn + ni * 16 + lr;
      if (OUT_BF16) {
        u16* C = (u16*)Cout;
#pragma unroll
        for (int r = 0; r < 4; ++r) C[(row0 + r) * N + col] = f2bf(acc[mi][ni][r]);
      } else {
        float* C = (float*)Cout;
#pragma unroll
        for (int r = 0; r < 4; ++r) C[(row0 + r) * N + col] = acc[mi][ni][r];
      }
    }
  }
}

// ---------------------------------------------------------------------------
// In-place RoPE on bf16 Q and K regions of qkvb [8192][3072]
// thread owns one (even,odd) pair = one 4B word.
// ---------------------------------------------------------------------------
__global__ __launch_bounds__(256) void rope_kernel(u16* __restrict__ qkvb,
                                                   const float2* __restrict__ tbl) {
  const int id = blockIdx.x * 256 + threadIdx.x;  // 2^23 threads
  const int qk = id >> 22;                        // 0 = Q, 1 = K
  const int r = id & 0x3FFFFF;
  const int row = r >> 9;    // 0..8191 (= b*2048+s)
  const int p = r & 511;     // pair within row
  const int h = p >> 5, i = p & 31;
  const int s = row & (SEQ - 1);
  const float2 cs = tbl[s * 32 + i];
  uint32_t* ptr = (uint32_t*)(qkvb + (size_t)row * 3072 + qk * 1024 + h * 64 + 2 * i);
  const uint32_t v = *ptr;
  const float x1 = bf2f((u16)(v & 0xffffu));
  const float x2 = bf2f((u16)(v >> 16));
  const float e = x1 * cs.x - x2 * cs.y;
  const float o = x1 * cs.y + x2 * cs.x;
  *ptr = (uint32_t)f2bf(e) | ((uint32_t)f2bf(o) << 16);
}

// ---------------------------------------------------------------------------
// V transpose: qkvb V region [b][s][h][d] -> Vt [b][h][d][s]   (bf16)
// ---------------------------------------------------------------------------
__global__ __launch_bounds__(256) void transpose_v_kernel(const u16* __restrict__ qkvb,
                                                          u16* __restrict__ Vt) {
  const int bh = blockIdx.y;
  const int b = bh >> 4, h = bh & 15;
  const int s = blockIdx.x * 256 + threadIdx.x;
  const u16* src = qkvb + ((size_t)b * SEQ + s) * 3072 + 2048 + h * 64;
  u16* dst = Vt + (size_t)bh * 64 * SEQ + s;
#pragma unroll
  for (int d = 0; d < 64; ++d) dst[(size_t)d * SEQ] = src[d];
}

// ---------------------------------------------------------------------------
// Causal flash attention. Grid (S/128, B*H); 4 independent waves/block,
// 32 q-rows per wave, KT=32. Swapped QK^T (mfma(K,Q)) => lane owns one q row,
// softmax reduce = 8 lane-local + shfl_xor(16,32). P re-fragmented via LDS.
// ---------------------------------------------------------------------------
__global__ __launch_bounds__(256) void attn_kernel(const u16* __restrict__ qkvb,
                                                   const u16* __restrict__ Vt,
                                                   u16* __restrict__ attn_out) {
  __shared__ __align__(16) u16 P_lds[4][2][16][48];  // [wave][qsub][q][k(padded)]
  const int tid = threadIdx.x;
  const int w = tid >> 6;
  const int l = tid & 63;
  const int g = l >> 4;
  const int lr = l & 15;
  const int bh = blockIdx.y;
  const int b = bh >> 4;
  const int h = bh & 15;
  const int wqb = blockIdx.x * 128 + w * 32;

  const u16* Qb = qkvb + (size_t)b * SEQ * 3072 + h * 64;
  const u16* Kb = Qb + 1024;
  const u16* Vb = Vt + (size_t)bh * 64 * SEQ;

  bf16x8 qf[2][2];
#pragma unroll
  for (int s = 0; s < 2; ++s)
#pragma unroll
    for (int hf = 0; hf < 2; ++hf)
      qf[s][hf] = *(const bf16x8*)(Qb + (size_t)(wqb + s * 16 + lr) * 3072 + hf * 32 + g * 8);

  f32x4 O[2][4] = {};
  float m_s[2] = {-INFINITY, -INFINITY};
  float l_s[2] = {0.f, 0.f};

  const int nkt = (wqb >> 5) + 1;
  for (int kt = 0; kt < nkt; ++kt) {
    const int kbase = kt * 32;
    bf16x8 kf[2][2];
#pragma unroll
    for (int kb = 0; kb < 2; ++kb)
#pragma unroll
      for (int hf = 0; hf < 2; ++hf)
        kf[kb][hf] = *(const bf16x8*)(Kb + (size_t)(kbase + kb * 16 + lr) * 3072 + hf * 32 + g * 8);
    bf16x8 vf[4];
#pragma unroll
    for (int dt = 0; dt < 4; ++dt)
      vf[dt] = *(const bf16x8*)(Vb + (size_t)(dt * 16 + lr) * SEQ + kbase + g * 8);

    const bool diag = (kt == nkt - 1);
#pragma unroll
    for (int s = 0; s < 2; ++s) {
      f32x4 st[2];
#pragma unroll
      for (int kb = 0; kb < 2; ++kb) {
        f32x4 c = {0.f, 0.f, 0.f, 0.f};
        c = MFMA_BF16(kf[kb][0], qf[s][0], c);
        c = MFMA_BF16(kf[kb][1], qf[s][1], c);
        st[kb] = c;  // S^T[k_local = kb*16 + g*4 + r][q = lr]
      }
      const int q = wqb + s * 16 + lr;
      float pv[8];
#pragma unroll
      for (int kb = 0; kb < 2; ++kb)
#pragma unroll
        for (int r = 0; r < 4; ++r) {
          const int kk = kbase + kb * 16 + g * 4 + r;
          float v = st[kb][r] * 0.125f;  // 1/sqrt(64)
          if (diag && kk > q) v = -1e30f;
          pv[kb * 4 + r] = v;
        }
      float pm = pv[0];
#pragma unroll
      for (int i = 1; i < 8; ++i) pm = fmaxf(pm, pv[i]);
      pm = fmaxf(pm, __shfl_xor(pm, 16));
      pm = fmaxf(pm, __shfl_xor(pm, 32));
      const float mnew = fmaxf(m_s[s], pm);
      const float corr = __expf(m_s[s] - mnew);
      float psum = 0.f;
#pragma unroll
      for (int i = 0; i < 8; ++i) { pv[i] = __expf(pv[i] - mnew); psum += pv[i]; }
      psum += __shfl_xor(psum, 16);
      psum += __shfl_xor(psum, 32);
      l_s[s] = l_s[s] * corr + psum;
      m_s[s] = mnew;
#pragma unroll
      for (int dt = 0; dt < 4; ++dt)
#pragma unroll
        for (int r = 0; r < 4; ++r) O[s][dt][r] *= corr;

      // P (bf16) -> LDS [q][k], then read back as PV B-fragment
      u16x4v pk0, pk1;
#pragma unroll
      for (int r = 0; r < 4; ++r) { pk0[r] = f2bf(pv[r]); pk1[r] = f2bf(pv[4 + r]); }
      *(u16x4v*)(&P_lds[w][s][lr][g * 4]) = pk0;
      *(u16x4v*)(&P_lds[w][s][lr][16 + g * 4]) = pk1;
      __asm__ volatile("s_waitcnt lgkmcnt(0)" ::: "memory");
      __builtin_amdgcn_sched_barrier(0);
      const bf16x8 pf = *(const bf16x8*)(&P_lds[w][s][lr][g * 8]);
#pragma unroll
      for (int dt = 0; dt < 4; ++dt) O[s][dt] = MFMA_BF16(vf[dt], pf, O[s][dt]);
    }
  }

#pragma unroll
  for (int s = 0; s < 2; ++s) {
    const float inv = 1.0f / l_s[s];
    const int q = wqb + s * 16 + lr;
    u16* orow = attn_out + ((size_t)b * SEQ + q) * 1024 + h * 64;
#pragma unroll
    for (int dt = 0; dt < 4; ++dt) {
      u16x4v pk;
#pragma unroll
      for (int r = 0; r < 4; ++r) pk[r] = f2bf(O[s][dt][r] * inv);
      *(u16x4v*)(orow + dt * 16 + g * 4) = pk;
    }
  }
}

// ---------------------------------------------------------------------------
extern "C" void kernel_launch(void* const* d_in, const int* in_sizes, int n_in,
                              void* d_out, int out_size, void* d_ws, size_t ws_size,
                              hipStream_t stream) {
  const float* x = (const float*)d_in[0];
  const float* wq = (const float*)d_in[1];
  const float* wk = (const float*)d_in[2];
  const float* wv = (const float*)d_in[3];
  const float* wo = (const float*)d_in[4];
  const int* tp = (const int*)d_in[5];

  char* ws = (char*)d_ws;
  u16* xb       = (u16*)(ws + 0);          // 8192x1024 bf16  (16 MB)
  u16* wqkvb    = (u16*)(ws + 16777216);   // 3072x1024 bf16  (6 MB)
  u16* wob      = (u16*)(ws + 23068672);   // 1024x1024 bf16  (2 MB)
  u16* qkvb     = (u16*)(ws + 25165824);   // 8192x3072 bf16  (48 MB)
  u16* Vt       = (u16*)(ws + 75497472);   // 64x64x2048 bf16 (16 MB)
  u16* attn_out = (u16*)(ws + 92274688);   // 8192x1024 bf16  (16 MB)
  float2* tbl   = (float2*)(ws + 109051904); // 2048x32 float2 (512 KB)

  cvt_kernel<<<12288, 256, 0, stream>>>((const float4*)x, (const float4*)wq,
                                        (const float4*)wk, (const float4*)wv,
                                        (const float4*)wo, (u16x4v*)xb,
                                        (u16x4v*)wqkvb, (u16x4v*)wob);
  rope_tbl_kernel<<<256, 256, 0, stream>>>(tp, tbl);
  gemm_bt<true><<<dim3(24, 64), 256, 0, stream>>>(xb, wqkvb, qkvb, 8192, 3072, 1024);
  rope_kernel<<<32768, 256, 0, stream>>>(qkvb, tbl);
  transpose_v_kernel<<<dim3(8, 64), 256, 0, stream>>>(qkvb, Vt);
  attn_kernel<<<dim3(16, 64), 256, 0, stream>>>(qkvb, Vt, attn_out);
  gemm_bt<false><<<dim3(8, 64), 256, 0, stream>>>(attn_out, wob, d_out, 8192, 1024, 1024);
}

// Round 2
// 348.363 us; speedup vs baseline: 1.3532x; 1.3532x over previous
//
#include <hip/hip_runtime.h>
#include <cstdint>
#include <cstddef>

typedef short bf16x8 __attribute__((ext_vector_type(8)));
typedef float f32x4 __attribute__((ext_vector_type(4)));
typedef unsigned short u16;
typedef u16 u16x4v __attribute__((ext_vector_type(4)));

#define SEQ 2048

static __device__ __forceinline__ u16 f2bf(float f) {
  uint32_t u = __builtin_bit_cast(uint32_t, f);
  u += 0x7fffu + ((u >> 16) & 1u);
  return (u16)(u >> 16);
}
static __device__ __forceinline__ float bf2f(u16 v) {
  uint32_t u = ((uint32_t)v) << 16;
  return __builtin_bit_cast(float, u);
}

#define MFMA_BF16(a, b, c) __builtin_amdgcn_mfma_f32_16x16x32_bf16((a), (b), (c), 0, 0, 0)

static __device__ __forceinline__ void gload_lds16(const void* g, void* l) {
  __builtin_amdgcn_global_load_lds((const __attribute__((address_space(1))) void*)g,
                                   (__attribute__((address_space(3))) void*)l, 16, 0, 0);
}

// ---------------------------------------------------------------------------
// fp32 -> bf16 conversion of x and weights (wq,wk,wv packed into one [3072][1024])
// ---------------------------------------------------------------------------
__global__ __launch_bounds__(256) void cvt_kernel(
    const float4* __restrict__ x, const float4* __restrict__ wq,
    const float4* __restrict__ wk, const float4* __restrict__ wv,
    const float4* __restrict__ wo, u16x4v* __restrict__ xb,
    u16x4v* __restrict__ wqkvb, u16x4v* __restrict__ wob) {
  const int id = blockIdx.x * 256 + threadIdx.x;  // 3,145,728 total
  const float4* src;
  u16x4v* dst;
  if (id < 2097152) { src = x + id; dst = xb + id; }
  else if (id < 2359296) { const int j = id - 2097152; src = wq + j; dst = wqkvb + j; }
  else if (id < 2621440) { const int j = id - 2359296; src = wk + j; dst = wqkvb + 262144 + j; }
  else if (id < 2883584) { const int j = id - 2621440; src = wv + j; dst = wqkvb + 524288 + j; }
  else { const int j = id - 2883584; src = wo + j; dst = wob + j; }
  const float4 v = *src;
  u16x4v o;
  o[0] = f2bf(v.x); o[1] = f2bf(v.y); o[2] = f2bf(v.z); o[3] = f2bf(v.w);
  *dst = o;
}

// ---------------------------------------------------------------------------
// RoPE cos/sin table: tbl[s*32+i] = (cos, sin)(pos[s] * theta^(-2i/64))
// ---------------------------------------------------------------------------
__global__ __launch_bounds__(256) void rope_tbl_kernel(const int* __restrict__ tp,
                                                       float2* __restrict__ tbl) {
  const int id = blockIdx.x * 256 + threadIdx.x;  // 65536
  const int s = id >> 5, i = id & 31;
  const float pos = (float)tp[s];
  const float freq = powf(10000.0f, -(float)(2 * i) / 64.0f);
  const float ang = pos * freq;
  float sv, cv;
  sincosf(ang, &sv, &cv);
  tbl[id] = make_float2(cv, sv);
}

// ---------------------------------------------------------------------------
// bf16 GEMM, NT layout: C[m][n] = sum_k A[m][k] * Bt[n][k]
// 128x128 tile, BK=64, 4 waves, global_load_lds(16B) with XOR-swizzled LDS.
// OUT_BF16 ? write bf16 : write fp32.
// ---------------------------------------------------------------------------
template <bool OUT_BF16>
__global__ __launch_bounds__(256) void gemm_bt(const u16* __restrict__ A,
                                               const u16* __restrict__ Bt,
                                               void* __restrict__ Cout,
                                               int M, int N, int K) {
  __shared__ __align__(16) u16 As[128 * 64];
  __shared__ __align__(16) u16 Bs[128 * 64];
  const int tid = threadIdx.x;
  const int w = tid >> 6;
  const int l = tid & 63;
  const int g = l >> 4;
  const int lr = l & 15;
  const int wm = (w >> 1) * 64;
  const int wn = (w & 1) * 64;
  const long tile_m = (long)blockIdx.y * 128;
  const long tile_n = (long)blockIdx.x * 128;

  const int lrow = l >> 3;               // row within chunk (== row&7)
  const int lcolsw = (l & 7) ^ lrow;     // swizzled 16B-chunk column in global

  f32x4 acc[4][4] = {};

  for (int k0 = 0; k0 < K; k0 += 64) {
#pragma unroll
    for (int cc = 0; cc < 4; ++cc) {
      const int c = w * 4 + cc;
      const int row = c * 8 + lrow;
      gload_lds16(A + (tile_m + row) * (long)K + k0 + lcolsw * 8, As + c * 512);
      gload_lds16(Bt + (tile_n + row) * (long)K + k0 + lcolsw * 8, Bs + c * 512);
    }
    __syncthreads();
#pragma unroll
    for (int kk = 0; kk < 2; ++kk) {
      bf16x8 af[4], bfr[4];
#pragma unroll
      for (int mi = 0; mi < 4; ++mi) {
        const int row = wm + mi * 16 + lr;
        const int cc = ((kk << 2) + g) ^ (row & 7);
        af[mi] = *(const bf16x8*)((const char*)As + row * 128 + cc * 16);
      }
#pragma unroll
      for (int ni = 0; ni < 4; ++ni) {
        const int row = wn + ni * 16 + lr;
        const int cc = ((kk << 2) + g) ^ (row & 7);
        bfr[ni] = *(const bf16x8*)((const char*)Bs + row * 128 + cc * 16);
      }
#pragma unroll
      for (int mi = 0; mi < 4; ++mi)
#pragma unroll
        for (int ni = 0; ni < 4; ++ni)
          acc[mi][ni] = MFMA_BF16(af[mi], bfr[ni], acc[mi][ni]);
    }
    __syncthreads();
  }

#pragma unroll
  for (int mi = 0; mi < 4; ++mi) {
#pragma unroll
    for (int ni = 0; ni < 4; ++ni) {
      const long row0 = tile_m + wm + mi * 16 + g * 4;
      const long col = tile_n + wn + ni * 16 + lr;
      if (OUT_BF16) {
        u16* C = (u16*)Cout;
#pragma unroll
        for (int r = 0; r < 4; ++r) C[(row0 + r) * N + col] = f2bf(acc[mi][ni][r]);
      } else {
        float* C = (float*)Cout;
#pragma unroll
        for (int r = 0; r < 4; ++r) C[(row0 + r) * N + col] = acc[mi][ni][r];
      }
    }
  }
}

// ---------------------------------------------------------------------------
// In-place RoPE on bf16 Q and K regions of qkvb [8192][3072]
// ---------------------------------------------------------------------------
__global__ __launch_bounds__(256) void rope_kernel(u16* __restrict__ qkvb,
                                                   const float2* __restrict__ tbl) {
  const int id = blockIdx.x * 256 + threadIdx.x;  // 2^23 threads
  const int qk = id >> 22;                        // 0 = Q, 1 = K
  const int r = id & 0x3FFFFF;
  const int row = r >> 9;    // 0..8191 (= b*2048+s)
  const int p = r & 511;     // pair within row
  const int h = p >> 5, i = p & 31;
  const int s = row & (SEQ - 1);
  const float2 cs = tbl[s * 32 + i];
  uint32_t* ptr = (uint32_t*)(qkvb + (size_t)row * 3072 + qk * 1024 + h * 64 + 2 * i);
  const uint32_t v = *ptr;
  const float x1 = bf2f((u16)(v & 0xffffu));
  const float x2 = bf2f((u16)(v >> 16));
  const float e = x1 * cs.x - x2 * cs.y;
  const float o = x1 * cs.y + x2 * cs.x;
  *ptr = (uint32_t)f2bf(e) | ((uint32_t)f2bf(o) << 16);
}

// ---------------------------------------------------------------------------
// V transpose: qkvb V region [b][s][h][d] -> Vt [b][h][d][s]   (bf16)
// ---------------------------------------------------------------------------
__global__ __launch_bounds__(256) void transpose_v_kernel(const u16* __restrict__ qkvb,
                                                          u16* __restrict__ Vt) {
  const int bh = blockIdx.y;
  const int b = bh >> 4, h = bh & 15;
  const int s = blockIdx.x * 256 + threadIdx.x;
  const u16* src = qkvb + ((size_t)b * SEQ + s) * 3072 + 2048 + h * 64;
  u16* dst = Vt + (size_t)bh * 64 * SEQ + s;
#pragma unroll
  for (int d = 0; d < 64; ++d) dst[(size_t)d * SEQ] = src[d];
}

// ---------------------------------------------------------------------------
// Causal flash attention, register-resident P (no LDS, no barriers).
// Grid (bh=64, qtile=16); 4 independent waves/block, 32 q-rows/wave, KT=32.
// Swapped QK^T (mfma(K,Q)) with PERMUTED K rows: for QK-MFMA kb, A-row i is
// loaded from actual K row (i>>2)*8 + kb*4 + (i&3), so the C output lands as
// reg r <-> k = g*8 + kb*4 + r, i.e. P is already in PV-B-fragment order
// in-lane (lane (g,lr) holds P[q=lr][k=g*8+j], j=0..7). No re-fragmentation.
// Heaviest q-tiles dispatch first (LJF) to fix the occupancy tail.
// ---------------------------------------------------------------------------
__global__ __launch_bounds__(256) void attn_kernel(const u16* __restrict__ qkvb,
                                                   const u16* __restrict__ Vt,
                                                   u16* __restrict__ attn_out) {
  const int tid = threadIdx.x;
  const int w = tid >> 6;
  const int l = tid & 63;
  const int g = l >> 4;
  const int lr = l & 15;
  const int bh = blockIdx.x;
  const int b = bh >> 4;
  const int h = bh & 15;
  const int qt = (int)gridDim.y - 1 - (int)blockIdx.y;  // heavy tiles first
  const int wqb = qt * 128 + w * 32;

  const u16* Qb = qkvb + (size_t)b * SEQ * 3072 + h * 64;
  const u16* Kb = Qb + 1024;
  const u16* Vb = Vt + (size_t)bh * 64 * SEQ;

  // permuted K row offset within tile for MFMA kb: (lr>>2)*8 + kb*4 + (lr&3)
  const int krow0 = ((lr >> 2) << 3) + (lr & 3);

  bf16x8 qf[2][2];
#pragma unroll
  for (int s = 0; s < 2; ++s)
#pragma unroll
    for (int hf = 0; hf < 2; ++hf)
      qf[s][hf] = *(const bf16x8*)(Qb + (size_t)(wqb + s * 16 + lr) * 3072 + hf * 32 + g * 8);

  f32x4 O[2][4] = {};
  float m_s[2] = {-INFINITY, -INFINITY};
  float l_s[2] = {0.f, 0.f};

  const int nkt = (wqb >> 5) + 1;

  // prefetch tile 0
  bf16x8 kf[2][2], vf[4];
#pragma unroll
  for (int kb = 0; kb < 2; ++kb)
#pragma unroll
    for (int hf = 0; hf < 2; ++hf)
      kf[kb][hf] = *(const bf16x8*)(Kb + (size_t)(krow0 + kb * 4) * 3072 + hf * 32 + g * 8);
#pragma unroll
  for (int dt = 0; dt < 4; ++dt)
    vf[dt] = *(const bf16x8*)(Vb + (size_t)(dt * 16 + lr) * SEQ + g * 8);

  for (int kt = 0; kt < nkt; ++kt) {
    const int kbase = kt * 32;
    // prefetch next tile (unconditional; reads land in valid ws memory and
    // are simply unused on the last iteration)
    bf16x8 kn[2][2], vn[4];
    {
      const int nb = kbase + 32;
#pragma unroll
      for (int kb = 0; kb < 2; ++kb)
#pragma unroll
        for (int hf = 0; hf < 2; ++hf)
          kn[kb][hf] = *(const bf16x8*)(Kb + (size_t)(nb + krow0 + kb * 4) * 3072 + hf * 32 + g * 8);
#pragma unroll
      for (int dt = 0; dt < 4; ++dt)
        vn[dt] = *(const bf16x8*)(Vb + (size_t)(dt * 16 + lr) * SEQ + nb + g * 8);
    }

    const bool diag = (kt == nkt - 1);
#pragma unroll
    for (int s = 0; s < 2; ++s) {
      f32x4 c0 = {0.f, 0.f, 0.f, 0.f}, c1 = {0.f, 0.f, 0.f, 0.f};
      c0 = MFMA_BF16(kf[0][0], qf[s][0], c0);
      c0 = MFMA_BF16(kf[0][1], qf[s][1], c0);
      c1 = MFMA_BF16(kf[1][0], qf[s][0], c1);
      c1 = MFMA_BF16(kf[1][1], qf[s][1], c1);
      // c{kb} reg r  <->  k = kbase + g*8 + kb*4 + r
      const int q = wqb + s * 16 + lr;
      float pv[8];
#pragma unroll
      for (int r = 0; r < 4; ++r) {
        float v0 = c0[r] * 0.125f;  // 1/sqrt(64)
        float v1 = c1[r] * 0.125f;
        if (diag) {
          if (kbase + g * 8 + r > q) v0 = -1e30f;
          if (kbase + g * 8 + 4 + r > q) v1 = -1e30f;
        }
        pv[r] = v0;
        pv[4 + r] = v1;
      }
      float pm = pv[0];
#pragma unroll
      for (int i = 1; i < 8; ++i) pm = fmaxf(pm, pv[i]);
      pm = fmaxf(pm, __shfl_xor(pm, 16));
      pm = fmaxf(pm, __shfl_xor(pm, 32));
      const float mnew = fmaxf(m_s[s], pm);
      const float corr = __expf(m_s[s] - mnew);
      float psum = 0.f;
#pragma unroll
      for (int i = 0; i < 8; ++i) { pv[i] = __expf(pv[i] - mnew); psum += pv[i]; }
      psum += __shfl_xor(psum, 16);
      psum += __shfl_xor(psum, 32);
      l_s[s] = l_s[s] * corr + psum;
      m_s[s] = mnew;
#pragma unroll
      for (int dt = 0; dt < 4; ++dt)
#pragma unroll
        for (int r = 0; r < 4; ++r) O[s][dt][r] *= corr;

      // P already in B-fragment order: pf[j] = P[q=lr][k = kbase + g*8 + j]
      bf16x8 pf;
#pragma unroll
      for (int j = 0; j < 8; ++j) pf[j] = (short)f2bf(pv[j]);
#pragma unroll
      for (int dt = 0; dt < 4; ++dt) O[s][dt] = MFMA_BF16(vf[dt], pf, O[s][dt]);
    }

#pragma unroll
    for (int kb = 0; kb < 2; ++kb)
#pragma unroll
      for (int hf = 0; hf < 2; ++hf) kf[kb][hf] = kn[kb][hf];
#pragma unroll
    for (int dt = 0; dt < 4; ++dt) vf[dt] = vn[dt];
  }

#pragma unroll
  for (int s = 0; s < 2; ++s) {
    const float inv = 1.0f / l_s[s];
    const int q = wqb + s * 16 + lr;
    u16* orow = attn_out + ((size_t)b * SEQ + q) * 1024 + h * 64;
#pragma unroll
    for (int dt = 0; dt < 4; ++dt) {
      u16x4v pk;
#pragma unroll
      for (int r = 0; r < 4; ++r) pk[r] = f2bf(O[s][dt][r] * inv);
      *(u16x4v*)(orow + dt * 16 + g * 4) = pk;
    }
  }
}

// ---------------------------------------------------------------------------
extern "C" void kernel_launch(void* const* d_in, const int* in_sizes, int n_in,
                              void* d_out, int out_size, void* d_ws, size_t ws_size,
                              hipStream_t stream) {
  const float* x = (const float*)d_in[0];
  const float* wq = (const float*)d_in[1];
  const float* wk = (const float*)d_in[2];
  const float* wv = (const float*)d_in[3];
  const float* wo = (const float*)d_in[4];
  const int* tp = (const int*)d_in[5];

  char* ws = (char*)d_ws;
  u16* xb       = (u16*)(ws + 0);          // 8192x1024 bf16  (16 MB)
  u16* wqkvb    = (u16*)(ws + 16777216);   // 3072x1024 bf16  (6 MB)
  u16* wob      = (u16*)(ws + 23068672);   // 1024x1024 bf16  (2 MB)
  u16* qkvb     = (u16*)(ws + 25165824);   // 8192x3072 bf16  (48 MB)
  u16* Vt       = (u16*)(ws + 75497472);   // 64x64x2048 bf16 (16 MB)
  u16* attn_out = (u16*)(ws + 92274688);   // 8192x1024 bf16  (16 MB)
  float2* tbl   = (float2*)(ws + 109051904); // 2048x32 float2 (512 KB)

  cvt_kernel<<<12288, 256, 0, stream>>>((const float4*)x, (const float4*)wq,
                                        (const float4*)wk, (const float4*)wv,
                                        (const float4*)wo, (u16x4v*)xb,
                                        (u16x4v*)wqkvb, (u16x4v*)wob);
  rope_tbl_kernel<<<256, 256, 0, stream>>>(tp, tbl);
  gemm_bt<true><<<dim3(24, 64), 256, 0, stream>>>(xb, wqkvb, qkvb, 8192, 3072, 1024);
  rope_kernel<<<32768, 256, 0, stream>>>(qkvb, tbl);
  transpose_v_kernel<<<dim3(8, 64), 256, 0, stream>>>(qkvb, Vt);
  attn_kernel<<<dim3(64, 16), 256, 0, stream>>>(qkvb, Vt, attn_out);
  gemm_bt<false><<<dim3(8, 64), 256, 0, stream>>>(attn_out, wob, d_out, 8192, 1024, 1024);
}

// Round 3
// 318.824 us; speedup vs baseline: 1.4786x; 1.0926x over previous
//
#include <hip/hip_runtime.h>
#include <cstdint>
#include <cstddef>

typedef short bf16x8 __attribute__((ext_vector_type(8)));
typedef float f32x4 __attribute__((ext_vector_type(4)));
typedef unsigned short u16;
typedef u16 u16x4v __attribute__((ext_vector_type(4)));
typedef uint32_t u32x4v __attribute__((ext_vector_type(4)));

#define SEQ 2048
// 0.125 (1/sqrt(64)) * log2(e), folded into Q at the rope-epilogue step
#define QSCALE 0.18033688011112042f
#define DEFER_THR 11.5415603f  // 8 * log2(e)

static __device__ __forceinline__ u16 f2bf(float f) {
  uint32_t u = __builtin_bit_cast(uint32_t, f);
  u += 0x7fffu + ((u >> 16) & 1u);
  return (u16)(u >> 16);
}

static __device__ __forceinline__ uint32_t cvtpk_bf16(float lo, float hi) {
  uint32_t r;
  asm("v_cvt_pk_bf16_f32 %0, %1, %2" : "=v"(r) : "v"(lo), "v"(hi));
  return r;
}

#define MFMA_BF16(a, b, c) __builtin_amdgcn_mfma_f32_16x16x32_bf16((a), (b), (c), 0, 0, 0)

static __device__ __forceinline__ void gload_lds16(const void* g, void* l) {
  __builtin_amdgcn_global_load_lds((const __attribute__((address_space(1))) void*)g,
                                   (__attribute__((address_space(3))) void*)l, 16, 0, 0);
}

// ---------------------------------------------------------------------------
// fp32 -> bf16 conversion. wq/wk/wv pack into one [3072][1024] Bt matrix.
// Q and K weight ROWS (output channels) are permuted within each 64-ch head:
// channel c -> (c>>1) + (c&1)*32, so RoPE pairs (2i,2i+1) land at (i, i+32).
// Any consistent d-permutation of Q and K preserves QK^T.
// ---------------------------------------------------------------------------
__global__ __launch_bounds__(256) void cvt_kernel(
    const float4* __restrict__ x, const float4* __restrict__ wq,
    const float4* __restrict__ wk, const float4* __restrict__ wv,
    const float4* __restrict__ wo, u16x4v* __restrict__ xb,
    u16x4v* __restrict__ wqkvb, u16x4v* __restrict__ wob) {
  const int id = blockIdx.x * 256 + threadIdx.x;  // 3,145,728 total
  const float4* src;
  u16x4v* dst;
  if (id < 2097152) { src = x + id; dst = xb + id; }
  else if (id < 2359296) {
    const int j = id - 2097152; const int e = j >> 8;
    const int ep = (e & ~63) | ((e & 63) >> 1) | ((e & 1) << 5);
    src = wq + j; dst = wqkvb + ep * 256 + (j & 255);
  } else if (id < 2621440) {
    const int j = id - 2359296; const int e = j >> 8;
    const int ep = (e & ~63) | ((e & 63) >> 1) | ((e & 1) << 5);
    src = wk + j; dst = wqkvb + 262144 + ep * 256 + (j & 255);
  } else if (id < 2883584) { const int j = id - 2621440; src = wv + j; dst = wqkvb + 524288 + j; }
  else { const int j = id - 2883584; src = wo + j; dst = wob + j; }
  const float4 v = *src;
  u16x4v o;
  o[0] = f2bf(v.x); o[1] = f2bf(v.y); o[2] = f2bf(v.z); o[3] = f2bf(v.w);
  *dst = o;
}

// ---------------------------------------------------------------------------
// RoPE cos/sin table: tbl[s*32+i] = (cos, sin)(pos[s] * theta^(-2i/64))
// ---------------------------------------------------------------------------
__global__ __launch_bounds__(256) void rope_tbl_kernel(const int* __restrict__ tp,
                                                       float2* __restrict__ tbl) {
  const int id = blockIdx.x * 256 + threadIdx.x;  // 65536
  const int s = id >> 5, i = id & 31;
  const float pos = (float)tp[s];
  const float freq = powf(10000.0f, -(float)(2 * i) / 64.0f);
  const float ang = pos * freq;
  float sv, cv;
  sincosf(ang, &sv, &cv);
  tbl[id] = make_float2(cv, sv);
}

// ---------------------------------------------------------------------------
// bf16 GEMM, NT layout: C[m][n] = sum_k A[m][k] * Bt[n][k]
// 128x128 tile, BK=64, 4 waves, global_load_lds(16B) with XOR-swizzled LDS.
// MODE 0: plain f32 C write (output projection).
// MODE 1: fused QKV epilogue — cols [0,2048) get RoPE applied in-register
//   (pairs are (ni, ni+2) thanks to the cvt channel permutation; Q also gets
//   QSCALE folded in) and are written bf16 to C (qkvb layout [M][3072]);
//   cols [2048,3072) are V and written TRANSPOSED to Vt[b*16+h][d][s].
// ---------------------------------------------------------------------------
template <int MODE>
__global__ __launch_bounds__(256) void gemm_bt(const u16* __restrict__ A,
                                               const u16* __restrict__ Bt,
                                               void* __restrict__ Cout,
                                               u16* __restrict__ Vt,
                                               const float2* __restrict__ tbl,
                                               int M, int N, int K) {
  __shared__ __align__(16) u16 As[128 * 64];
  __shared__ __align__(16) u16 Bs[128 * 64];
  const int tid = threadIdx.x;
  const int w = tid >> 6;
  const int l = tid & 63;
  const int g = l >> 4;
  const int lr = l & 15;
  const int wm = (w >> 1) * 64;
  const int wn = (w & 1) * 64;
  const long tile_m = (long)blockIdx.y * 128;
  const long tile_n = (long)blockIdx.x * 128;

  const int lrow = l >> 3;               // row within chunk (== row&7)
  const int lcolsw = (l & 7) ^ lrow;     // swizzled 16B-chunk column in global

  f32x4 acc[4][4] = {};

  for (int k0 = 0; k0 < K; k0 += 64) {
#pragma unroll
    for (int cc = 0; cc < 4; ++cc) {
      const int c = w * 4 + cc;
      const int row = c * 8 + lrow;
      gload_lds16(A + (tile_m + row) * (long)K + k0 + lcolsw * 8, As + c * 512);
      gload_lds16(Bt + (tile_n + row) * (long)K + k0 + lcolsw * 8, Bs + c * 512);
    }
    __syncthreads();
#pragma unroll
    for (int kk = 0; kk < 2; ++kk) {
      bf16x8 af[4], bfr[4];
#pragma unroll
      for (int mi = 0; mi < 4; ++mi) {
        const int row = wm + mi * 16 + lr;
        const int cc = ((kk << 2) + g) ^ (row & 7);
        af[mi] = *(const bf16x8*)((const char*)As + row * 128 + cc * 16);
      }
#pragma unroll
      for (int ni = 0; ni < 4; ++ni) {
        const int row = wn + ni * 16 + lr;
        const int cc = ((kk << 2) + g) ^ (row & 7);
        bfr[ni] = *(const bf16x8*)((const char*)Bs + row * 128 + cc * 16);
      }
#pragma unroll
      for (int mi = 0; mi < 4; ++mi)
#pragma unroll
        for (int ni = 0; ni < 4; ++ni)
          acc[mi][ni] = MFMA_BF16(af[mi], bfr[ni], acc[mi][ni]);
    }
    __syncthreads();
  }

  if constexpr (MODE == 0) {
    float* C = (float*)Cout;
#pragma unroll
    for (int mi = 0; mi < 4; ++mi) {
#pragma unroll
      for (int ni = 0; ni < 4; ++ni) {
        const long row0 = tile_m + wm + mi * 16 + g * 4;
        const long col = tile_n + wn + ni * 16 + lr;
#pragma unroll
        for (int r = 0; r < 4; ++r) C[(row0 + r) * N + col] = acc[mi][ni][r];
      }
    }
  } else {
    u16* C = (u16*)Cout;
    if (tile_n < 2048) {
      // Q/K: RoPE in-register. x1 at d'=i (ni in {0,1}), x2 at d'=i+32 (ni+2).
      const float scale = (tile_n < 1024) ? QSCALE : 1.0f;
#pragma unroll
      for (int mi = 0; mi < 4; ++mi) {
        const long row0 = tile_m + wm + mi * 16 + g * 4;
#pragma unroll
        for (int np = 0; np < 2; ++np) {
          const long col = tile_n + wn + np * 16 + lr;
          const int i = (int)col & 31;
#pragma unroll
          for (int r = 0; r < 4; ++r) {
            const long row = row0 + r;
            const float2 cs = tbl[((int)row & (SEQ - 1)) * 32 + i];
            const float x1 = acc[mi][np][r];
            const float x2 = acc[mi][np + 2][r];
            C[row * N + col]      = f2bf((x1 * cs.x - x2 * cs.y) * scale);
            C[row * N + col + 32] = f2bf((x1 * cs.y + x2 * cs.x) * scale);
          }
        }
      }
    } else {
      // V: write transposed to Vt[b*16+h][d][s], 8B per (mi,ni) per lane
#pragma unroll
      for (int mi = 0; mi < 4; ++mi) {
        const long row0 = tile_m + wm + mi * 16 + g * 4;
        const int bb = (int)(row0 >> 11);
        const int s0 = (int)row0 & (SEQ - 1);
#pragma unroll
        for (int ni = 0; ni < 4; ++ni) {
          const int hd = (int)(tile_n + wn + ni * 16 + lr) - 2048;
          u16x4v pk;
#pragma unroll
          for (int r = 0; r < 4; ++r) pk[r] = f2bf(acc[mi][ni][r]);
          *(u16x4v*)(Vt + ((size_t)(bb * 16 + (hd >> 6)) * 64 + (hd & 63)) * SEQ + s0) = pk;
        }
      }
    }
  }
}

// ---------------------------------------------------------------------------
// Causal flash attention, register-resident P (no LDS, no barriers).
// Grid (bh=64, pair=8); block y handles q-tiles (15-y) then (y): every wave
// processes 62+2w k-columns -> balanced residency for the whole kernel.
// KT=64 per online-softmax step; exp2 domain (scale pre-folded into Q);
// defer-max rescale (T13); P packed via v_cvt_pk_bf16_f32.
// Swapped QK^T (mfma(K,Q)) with PERMUTED K rows: for MFMA X, A-row i comes
// from K row (X>>1)*32 + (i>>2)*8 + (X&1)*4 + (i&3), so the C output lands
// as reg r <-> k = (X>>1)*32 + g*8 + (X&1)*4 + r: P is already in
// PV-B-fragment order in-lane. No cross-lane P movement.
// ---------------------------------------------------------------------------
__global__ __launch_bounds__(256, 2) void attn_kernel(const u16* __restrict__ qkvb,
                                                      const u16* __restrict__ Vt,
                                                      u16* __restrict__ attn_out) {
  const int tid = threadIdx.x;
  const int w = tid >> 6;
  const int l = tid & 63;
  const int g = l >> 4;
  const int lr = l & 15;
  const int bh = blockIdx.x;
  const int b = bh >> 4;
  const int h = bh & 15;

  const u16* Qb = qkvb + (size_t)b * SEQ * 3072 + h * 64;
  const u16* Kb = Qb + 1024;
  const u16* Vb = Vt + (size_t)bh * 64 * SEQ;

  // permuted K row offset within a 32-row block, for MFMA half (X&1):
  const int krow0 = ((lr >> 2) << 3) + (lr & 3);

#pragma unroll
  for (int ph = 0; ph < 2; ++ph) {
    const int qt = ph ? (int)blockIdx.y : 15 - (int)blockIdx.y;
    const int wqb = qt * 128 + w * 32;

    bf16x8 qf[2][2];
#pragma unroll
    for (int s = 0; s < 2; ++s)
#pragma unroll
      for (int hf = 0; hf < 2; ++hf)
        qf[s][hf] = *(const bf16x8*)(Qb + (size_t)(wqb + s * 16 + lr) * 3072 + hf * 32 + g * 8);

    f32x4 O[2][4] = {};
    float m_s[2] = {-1e38f, -1e38f};
    float l_s[2] = {0.f, 0.f};

    const int n32 = (wqb >> 5) + 1;
    const int n64 = (n32 + 1) >> 1;

    bf16x8 kf[4][2];
#pragma unroll
    for (int X = 0; X < 4; ++X)
#pragma unroll
      for (int hf = 0; hf < 2; ++hf)
        kf[X][hf] = *(const bf16x8*)(Kb + (size_t)((X >> 1) * 32 + krow0 + (X & 1) * 4) * 3072 + hf * 32 + g * 8);

    for (int kt = 0; kt < n64; ++kt) {
      const int kbase = kt * 64;
      // prefetch next K tile (reads past the K region stay inside d_ws)
      bf16x8 kn[4][2];
      {
        const int nb = kbase + 64;
#pragma unroll
        for (int X = 0; X < 4; ++X)
#pragma unroll
          for (int hf = 0; hf < 2; ++hf)
            kn[X][hf] = *(const bf16x8*)(Kb + (size_t)(nb + (X >> 1) * 32 + krow0 + (X & 1) * 4) * 3072 + hf * 32 + g * 8);
      }
      // V for current tile (issued early; consumed after QK+softmax)
      bf16x8 vf[4][2];
#pragma unroll
      for (int dt = 0; dt < 4; ++dt)
#pragma unroll
        for (int hv = 0; hv < 2; ++hv)
          vf[dt][hv] = *(const bf16x8*)(Vb + (size_t)(dt * 16 + lr) * SEQ + kbase + hv * 32 + g * 8);

      const bool diag = (kt == n64 - 1);
#pragma unroll
      for (int s = 0; s < 2; ++s) {
        f32x4 c[4] = {};
#pragma unroll
        for (int X = 0; X < 4; ++X) {
          c[X] = MFMA_BF16(kf[X][0], qf[s][0], c[X]);
          c[X] = MFMA_BF16(kf[X][1], qf[s][1], c[X]);
        }
        const int q = wqb + s * 16 + lr;
        float t[16];
#pragma unroll
        for (int X = 0; X < 4; ++X)
#pragma unroll
          for (int r = 0; r < 4; ++r) {
            float v = c[X][r];
            if (diag) {
              const int kk = kbase + (X >> 1) * 32 + g * 8 + (X & 1) * 4 + r;
              if (kk > q) v = -1e30f;
            }
            t[X * 4 + r] = v;
          }
        // tree max over 16
        float m01 = fmaxf(t[0], t[1]), m23 = fmaxf(t[2], t[3]);
        float m45 = fmaxf(t[4], t[5]), m67 = fmaxf(t[6], t[7]);
        float m89 = fmaxf(t[8], t[9]), mab = fmaxf(t[10], t[11]);
        float mcd = fmaxf(t[12], t[13]), mef = fmaxf(t[14], t[15]);
        float pm = fmaxf(fmaxf(fmaxf(m01, m23), fmaxf(m45, m67)),
                         fmaxf(fmaxf(m89, mab), fmaxf(mcd, mef)));
        pm = fmaxf(pm, __shfl_xor(pm, 16));
        pm = fmaxf(pm, __shfl_xor(pm, 32));
        if (!__all(pm <= m_s[s] + DEFER_THR)) {
          const float mnew = fmaxf(m_s[s], pm);
          const float corr = __builtin_amdgcn_exp2f(m_s[s] - mnew);
          l_s[s] *= corr;
#pragma unroll
          for (int dt = 0; dt < 4; ++dt)
#pragma unroll
            for (int r = 0; r < 4; ++r) O[s][dt][r] *= corr;
          m_s[s] = mnew;
        }
        float p[16];
        float psum = 0.f;
#pragma unroll
        for (int i = 0; i < 16; ++i) {
          p[i] = __builtin_amdgcn_exp2f(t[i] - m_s[s]);
          psum += p[i];
        }
        psum += __shfl_xor(psum, 16);
        psum += __shfl_xor(psum, 32);
        l_s[s] += psum;

        u32x4v pk0, pk1;
#pragma unroll
        for (int j = 0; j < 4; ++j) {
          pk0[j] = cvtpk_bf16(p[2 * j], p[2 * j + 1]);
          pk1[j] = cvtpk_bf16(p[8 + 2 * j], p[8 + 2 * j + 1]);
        }
        const bf16x8 pf0 = __builtin_bit_cast(bf16x8, pk0);
        const bf16x8 pf1 = __builtin_bit_cast(bf16x8, pk1);
#pragma unroll
        for (int dt = 0; dt < 4; ++dt) {
          O[s][dt] = MFMA_BF16(vf[dt][0], pf0, O[s][dt]);
          O[s][dt] = MFMA_BF16(vf[dt][1], pf1, O[s][dt]);
        }
      }
#pragma unroll
      for (int X = 0; X < 4; ++X)
#pragma unroll
        for (int hf = 0; hf < 2; ++hf) kf[X][hf] = kn[X][hf];
    }

#pragma unroll
    for (int s = 0; s < 2; ++s) {
      const float inv = 1.0f / l_s[s];
      const int q = wqb + s * 16 + lr;
      u16* orow = attn_out + ((size_t)b * SEQ + q) * 1024 + h * 64;
#pragma unroll
      for (int dt = 0; dt < 4; ++dt) {
        u16x4v pk;
#pragma unroll
        for (int r = 0; r < 4; ++r) pk[r] = f2bf(O[s][dt][r] * inv);
        *(u16x4v*)(orow + dt * 16 + g * 4) = pk;
      }
    }
  }
}

// ---------------------------------------------------------------------------
extern "C" void kernel_launch(void* const* d_in, const int* in_sizes, int n_in,
                              void* d_out, int out_size, void* d_ws, size_t ws_size,
                              hipStream_t stream) {
  const float* x = (const float*)d_in[0];
  const float* wq = (const float*)d_in[1];
  const float* wk = (const float*)d_in[2];
  const float* wv = (const float*)d_in[3];
  const float* wo = (const float*)d_in[4];
  const int* tp = (const int*)d_in[5];

  char* ws = (char*)d_ws;
  u16* xb       = (u16*)(ws + 0);          // 8192x1024 bf16  (16 MB)
  u16* wqkvb    = (u16*)(ws + 16777216);   // 3072x1024 bf16  (6 MB)
  u16* wob      = (u16*)(ws + 23068672);   // 1024x1024 bf16  (2 MB)
  u16* qkvb     = (u16*)(ws + 25165824);   // 8192x3072 bf16  (48 MB)
  u16* Vt       = (u16*)(ws + 75497472);   // 64x64x2048 bf16 (16 MB)
  u16* attn_out = (u16*)(ws + 92274688);   // 8192x1024 bf16  (16 MB)
  float2* tbl   = (float2*)(ws + 109051904); // 2048x32 float2 (512 KB)

  cvt_kernel<<<12288, 256, 0, stream>>>((const float4*)x, (const float4*)wq,
                                        (const float4*)wk, (const float4*)wv,
                                        (const float4*)wo, (u16x4v*)xb,
                                        (u16x4v*)wqkvb, (u16x4v*)wob);
  rope_tbl_kernel<<<256, 256, 0, stream>>>(tp, tbl);
  gemm_bt<1><<<dim3(24, 64), 256, 0, stream>>>(xb, wqkvb, qkvb, Vt, tbl, 8192, 3072, 1024);
  attn_kernel<<<dim3(64, 8), 256, 0, stream>>>(qkvb, Vt, attn_out);
  gemm_bt<0><<<dim3(8, 64), 256, 0, stream>>>(attn_out, wob, d_out, nullptr, nullptr, 8192, 1024, 1024);
}